// Round 6
// baseline (120.675 us; speedup 1.0000x reference)
//
#include <hip/hip_runtime.h>

#define B_SZ 16384
#define N_SP 129
#define GRID 512
#define BLOCK 256

typedef _Float16 half8 __attribute__((ext_vector_type(8)));
typedef float float4v __attribute__((ext_vector_type(4)));

// ws layout:
//   halves [0, 12288): 24 B-frags, 64 lanes x 8 f16 each; frag = tbl*8 + t*4 + g
//     (tbl: 0=tw 1=qxt 2=qtt_sym), element ((frag*64 + lane)*8 + j)
//   floats from WS_F32_BASE: twy[64] qxy[64] qyt[64] lint[64] liny[1]
#define WS_F32_BASE 6144
#define WS_TWY  (WS_F32_BASE)
#define WS_QXY  (WS_F32_BASE + 64)
#define WS_QYT  (WS_F32_BASE + 128)
#define WS_LINT (WS_F32_BASE + 192)
#define WS_LINY (WS_F32_BASE + 256)

// index into main_w for quadratic pair (i<j), N=129: N + i*(2N-i-1)/2 + (j-i-1)
__device__ __forceinline__ int qidx(int i, int j) {
  return N_SP + i * (2 * N_SP - i - 1) / 2 + (j - i - 1);
}

// tanh(x) = 1 - 2/(e^{2x}+1): monotone, stable both tails; clamp absorbs garbage rows
__device__ __forceinline__ float fast_tanh(float x) {
  float xc = fminf(fmaxf(x, -15.f), 15.f);
  float e = __expf(2.f * xc);
  return 1.f - 2.f / (e + 1.f);
}

__global__ void setup_kernel(const float* __restrict__ mw, const float* __restrict__ tw,
                             float* __restrict__ wsf, float* __restrict__ out) {
  int t = blockIdx.x * blockDim.x + threadIdx.x;
  if (t == 0) { out[B_SZ] = 0.f; out[B_SZ + 1] = 0.f; }
  if (t < 12288) {
    int frag = t >> 9, e = t & 511;
    int lane = e >> 3, j = e & 7;
    int tbl = frag >> 3, tg = frag & 7;
    int kt = tg >> 2, g = tg & 3;
    int k = kt * 32 + (lane >> 4) * 8 + j;   // K index (d or u), 0..63
    int n = (lane & 15) + 16 * g;            // N index (unit or i), 0..63
    float v;
    if (tbl == 0) {
      v = tw[n * 65 + k];                    // B[k][n] = tw[n][k]
    } else if (tbl == 1) {
      v = mw[qidx(n, 65 + k)];               // Qxt[i=n][u=k]
    } else {
      v = 0.f;
      if (n != k) {
        int a = n < k ? n : k, b = n < k ? k : n;
        v = mw[qidx(65 + a, 65 + b)];        // Qtt_sym
      }
    }
    ((_Float16*)wsf)[t] = (_Float16)v;
  } else if (t < 12352) {
    int u = t - 12288; wsf[WS_TWY + u] = tw[u * 65 + 64];
  } else if (t < 12416) {
    int i = t - 12352; wsf[WS_QXY + i] = mw[qidx(i, 64)];
  } else if (t < 12480) {
    int u = t - 12416; wsf[WS_QYT + u] = mw[qidx(64, 65 + u)];
  } else if (t < 12544) {
    int u = t - 12480; wsf[WS_LINT + u] = mw[65 + u];
  } else if (t == 12544) {
    wsf[WS_LINY] = mw[64];
  }
}

__global__ __launch_bounds__(BLOCK, 2) void main_kernel(
    const float* __restrict__ inps, const float* __restrict__ tb,
    const float* __restrict__ wsf, float* __restrict__ out) {
  // per-wave x / dt tiles: 16 rows x stride 72 f16 (rows 8..15 uninit garbage:
  // they feed only MFMA C-rows 8..15, never consumed; tanh clamp keeps it finite)
  __shared__ __align__(16) _Float16 s_x[4 * 1152];
  __shared__ __align__(16) _Float16 s_dt[4 * 1152];

  const int tid = threadIdx.x;
  const int l = tid & 63, wib = tid >> 6;
  const int wave = (blockIdx.x << 2) + wib;  // 0..2047
  const int b0 = wave << 3;                  // 8 rows per wave
  const int q = l >> 4, m = l & 15;
  const bool act = (q < 2);

  _Float16* xw = s_x + wib * 1152;
  _Float16* dw = s_dt + wib * 1152;

  // ---- issue ALL long-latency loads first (independent of each other) ----
  const half8* fragv = (const half8*)wsf;
  half8 f_tw[8], f_qxt[8], f_qtt[8];
#pragma unroll
  for (int f = 0; f < 8; f++) {
    f_tw[f]  = fragv[f * 64 + l];
    f_qxt[f] = fragv[(8 + f) * 64 + l];
    f_qtt[f] = fragv[(16 + f) * 64 + l];
  }
  float twyv[4], tbv[4], qxyv[4], qytv[4], lintv[4];
#pragma unroll
  for (int g = 0; g < 4; g++) {
    int u = m + 16 * g;
    twyv[g] = wsf[WS_TWY + u];
    qxyv[g] = wsf[WS_QXY + u];
    qytv[g] = wsf[WS_QYT + u];
    lintv[g] = wsf[WS_LINT + u];
    tbv[g] = tb[u];
  }
  const float liny = wsf[WS_LINY];

  // ---- x staging: 8 rows x 65 f32 -> f16 LDS, stride 72 (16B-aligned frags) ----
  {
    const float4* src4 = (const float4*)(inps + b0 * 65);  // 130 float4, 16B aligned
    float4 v0 = src4[l];
    float4 v1 = src4[64 + l];
#pragma unroll
    for (int c = 0; c < 4; c++) {
      unsigned idx = l * 4 + c;
      unsigned row = idx / 65u, col = idx - row * 65u;
      xw[row * 72 + col] = (_Float16)((const float*)&v0)[c];
    }
#pragma unroll
    for (int c = 0; c < 4; c++) {
      unsigned idx = (64 + l) * 4 + c;
      unsigned row = idx / 65u, col = idx - row * 65u;
      xw[row * 72 + col] = (_Float16)((const float*)&v1)[c];
    }
    if (l < 2) {
      float4 v2 = src4[128 + l];
#pragma unroll
      for (int c = 0; c < 4; c++) {
        unsigned idx = (128 + l) * 4 + c;
        unsigned row = idx / 65u, col = idx - row * 65u;
        xw[row * 72 + col] = (_Float16)((const float*)&v2)[c];
      }
    }
  }
  __syncthreads();  // waves share s_x/s_dt arrays' LDS block but not data; barrier
                    // only orders the per-wave region writes vs frag reads cheaply

  // A-frags of x: lane holds row m, k = t*32 + q*8 + j  (ds_read_b128)
  half8 ax[2];
#pragma unroll
  for (int t = 0; t < 2; t++)
    ax[t] = *(const half8*)(xw + m * 72 + t * 32 + q * 8);

  // matvec: w_pre C-layout (row=q*4+r, unit=m+16g)
  float4v acc[4];
#pragma unroll
  for (int g = 0; g < 4; g++) { acc[g][0] = 0.f; acc[g][1] = 0.f; acc[g][2] = 0.f; acc[g][3] = 0.f; }
#pragma unroll
  for (int g = 0; g < 4; g++)
#pragma unroll
    for (int t = 0; t < 2; t++)
      acc[g] = __builtin_amdgcn_mfma_f32_16x16x32_f16(ax[t], f_tw[t * 4 + g], acc[g], 0, 0, 0);

  // epilogue 1: tanh pair, penalties, dt -> LDS (f16) for A-relayout
  float yv[4];
#pragma unroll
  for (int r = 0; r < 4; r++) yv[r] = (float)xw[(q * 4 + r) * 72 + 64];
  float dtv[4][4], stv[4][4];
  float pint = 0.f, pneut = 0.f;
#pragma unroll
  for (int g = 0; g < 4; g++)
#pragma unroll
    for (int r = 0; r < 4; r++) {
      float wpre = acc[g][r] + tbv[g];
      float w1 = wpre + twyv[g] * yv[r];
      float w2 = wpre - twyv[g] * yv[r];
      float t1 = fast_tanh(w1), t2 = fast_tanh(w2);
      float dt = t1 - t2, st = t1 + t2;
      dtv[g][r] = dt; stv[g][r] = st;
      if (act) {
        float a1 = 1.f - t1 * t1, a2 = 1.f - t2 * t2;
        pint += a1 * a1 + a2 * a2;
        float nv = t2 * w2 - t1 * w1;
        pneut += nv * nv;
        dw[(q * 4 + r) * 72 + m + 16 * g] = (_Float16)dt;  // same-wave LDS round-trip
      }
    }

  // A-frags of dt (rows 8..15 garbage -> only unused C rows)
  half8 adt[2];
#pragma unroll
  for (int t = 0; t < 2; t++)
    adt[t] = *(const half8*)(dw + m * 72 + t * 32 + q * 8);

  float4v rxt[4], rtt[4];
#pragma unroll
  for (int g = 0; g < 4; g++) {
    rxt[g][0] = 0.f; rxt[g][1] = 0.f; rxt[g][2] = 0.f; rxt[g][3] = 0.f;
    rtt[g][0] = 0.f; rtt[g][1] = 0.f; rtt[g][2] = 0.f; rtt[g][3] = 0.f;
  }
#pragma unroll
  for (int g = 0; g < 4; g++)
#pragma unroll
    for (int t = 0; t < 2; t++) {
      rxt[g] = __builtin_amdgcn_mfma_f32_16x16x32_f16(adt[t], f_qxt[t * 4 + g], rxt[g], 0, 0, 0);
      rtt[g] = __builtin_amdgcn_mfma_f32_16x16x32_f16(adt[t], f_qtt[t * 4 + g], rtt[g], 0, 0, 0);
    }

  // final assembly: per (row=q*4+r, i=m+16g), reduce over g then lanes m
  float creg[4] = {0.f, 0.f, 0.f, 0.f};
#pragma unroll
  for (int g = 0; g < 4; g++)
#pragma unroll
    for (int r = 0; r < 4; r++) {
      float xv = (float)xw[(q * 4 + r) * 72 + m + 16 * g];
      creg[r] += xv * (2.f * yv[r] * qxyv[g] + rxt[g][r])
               + yv[r] * stv[g][r] * qytv[g]
               + 0.5f * stv[g][r] * rtt[g][r]
               + lintv[g] * dtv[g][r];
    }
#pragma unroll
  for (int r = 0; r < 4; r++) {
    float c = creg[r];
    c += __shfl_xor(c, 1); c += __shfl_xor(c, 2);
    c += __shfl_xor(c, 4); c += __shfl_xor(c, 8);
    if (act && m == 0) out[b0 + q * 4 + r] = 1.f + 2.f * yv[r] * liny + c;
  }

  // penalties: wave reduce -> one atomic pair per wave (device scope, slots
  // zeroed by setup_kernel, stream-ordered before us)
#pragma unroll
  for (int off = 1; off < 64; off <<= 1) {
    pint += __shfl_xor(pint, off);
    pneut += __shfl_xor(pneut, off);
  }
  if (l == 0) {
    atomicAdd(&out[B_SZ], pint * (1.f / 300.f));
    atomicAdd(&out[B_SZ + 1], pneut);
  }
}

extern "C" void kernel_launch(void* const* d_in, const int* in_sizes, int n_in,
                              void* d_out, int out_size, void* d_ws, size_t ws_size,
                              hipStream_t stream) {
  const float* inps = (const float*)d_in[0];
  const float* tw   = (const float*)d_in[1];
  const float* tb   = (const float*)d_in[2];
  const float* mw   = (const float*)d_in[3];
  float* out = (float*)d_out;
  float* wsf = (float*)d_ws;
  setup_kernel<<<50, 256, 0, stream>>>(mw, tw, wsf, out);
  main_kernel<<<GRID, BLOCK, 0, stream>>>(inps, tb, wsf, out);
}

// Round 8
// 71.211 us; speedup vs baseline: 1.6946x; 1.6946x over previous
//
#include <hip/hip_runtime.h>

#define B_SZ 16384
#define N_SP 129
#define GRID 512
#define BLOCK 256

typedef _Float16 half8 __attribute__((ext_vector_type(8)));
typedef float float4v __attribute__((ext_vector_type(4)));

// ws layout:
//   halves [0, 12288) (= floats [0,6144)): 24 B-frags, 64 lanes x 8 f16 each;
//     frag = tbl*8 + t*4 + g (tbl: 0=tw 1=qxt 2=qtt_sym), element ((frag*64+lane)*8+j)
//   floats: twy[64] qxy[64] qyt[64] lint[64] liny | p1[512] p2[512]
#define WS_TWY  6144
#define WS_QXY  6208
#define WS_QYT  6272
#define WS_LINT 6336
#define WS_LINY 6400
#define WS_P1   6464
#define WS_P2   6976

// index into main_w for quadratic pair (i<j), N=129: N + i*(2N-i-1)/2 + (j-i-1)
__device__ __forceinline__ int qidx(int i, int j) {
  return N_SP + i * (2 * N_SP - i - 1) / 2 + (j - i - 1);
}

// tanh(x) = 1 - 2/(e^{2x}+1): monotone, stable both tails; clamp absorbs garbage rows
__device__ __forceinline__ float fast_tanh(float x) {
  float xc = fminf(fmaxf(x, -15.f), 15.f);
  float e = __expf(2.f * xc);
  return 1.f - 2.f / (e + 1.f);
}

__global__ void setup_kernel(const float* __restrict__ mw, const float* __restrict__ tw,
                             float* __restrict__ wsf) {
  int t = blockIdx.x * blockDim.x + threadIdx.x;
  if (t < 12288) {
    int frag = t >> 9, e = t & 511;
    int lane = e >> 3, j = e & 7;
    int tbl = frag >> 3, tg = frag & 7;
    int kt = tg >> 2, g = tg & 3;
    int k = kt * 32 + (lane >> 4) * 8 + j;   // K index (d or u), 0..63
    int n = (lane & 15) + 16 * g;            // N index (unit or i), 0..63
    float v;
    if (tbl == 0) {
      v = tw[n * 65 + k];                    // B[k][n] = tw[n][k]
    } else if (tbl == 1) {
      v = mw[qidx(n, 65 + k)];               // Qxt[i=n][u=k]
    } else {
      v = 0.f;
      if (n != k) {
        int a = n < k ? n : k, b = n < k ? k : n;
        v = mw[qidx(65 + a, 65 + b)];        // Qtt_sym
      }
    }
    ((_Float16*)wsf)[t] = (_Float16)v;
  } else if (t < 12352) {
    int u = t - 12288; wsf[WS_TWY + u] = tw[u * 65 + 64];
  } else if (t < 12416) {
    int i = t - 12352; wsf[WS_QXY + i] = mw[qidx(i, 64)];
  } else if (t < 12480) {
    int u = t - 12416; wsf[WS_QYT + u] = mw[qidx(64, 65 + u)];
  } else if (t < 12544) {
    int u = t - 12480; wsf[WS_LINT + u] = mw[65 + u];
  } else if (t == 12544) {
    wsf[WS_LINY] = mw[64];
  }
}

__global__ __launch_bounds__(BLOCK, 2) void main_kernel(
    const float* __restrict__ inps, const float* __restrict__ tb,
    float* __restrict__ wsf, float* __restrict__ out) {
  // per-wave x / dt tiles: 16 rows x stride 72 f16 (rows 8..15 uninit garbage:
  // they feed only MFMA C-rows 8..15, never consumed; tanh clamp keeps it finite)
  __shared__ __align__(16) _Float16 s_x[4 * 1152];
  __shared__ __align__(16) _Float16 s_dt[4 * 1152];
  __shared__ float s_red[8];

  const int tid = threadIdx.x;
  const int l = tid & 63, wib = tid >> 6;
  const int wave = (blockIdx.x << 2) + wib;  // 0..2047
  const int b0 = wave << 3;                  // 8 rows per wave
  const int q = l >> 4, m = l & 15;
  const bool act = (q < 2);

  _Float16* xw = s_x + wib * 1152;
  _Float16* dw = s_dt + wib * 1152;

  // ---- issue ALL long-latency loads first (independent of each other) ----
  const half8* fragv = (const half8*)wsf;
  half8 f_tw[8], f_qxt[8], f_qtt[8];
#pragma unroll
  for (int f = 0; f < 8; f++) {
    f_tw[f]  = fragv[f * 64 + l];
    f_qxt[f] = fragv[(8 + f) * 64 + l];
    f_qtt[f] = fragv[(16 + f) * 64 + l];
  }
  float twyv[4], tbv[4], qxyv[4], qytv[4], lintv[4];
#pragma unroll
  for (int g = 0; g < 4; g++) {
    int u = m + 16 * g;
    twyv[g] = wsf[WS_TWY + u];
    qxyv[g] = wsf[WS_QXY + u];
    qytv[g] = wsf[WS_QYT + u];
    lintv[g] = wsf[WS_LINT + u];
    tbv[g] = tb[u];
  }
  const float liny = wsf[WS_LINY];

  // ---- x staging: 8 rows x 65 f32 -> f16 LDS, stride 72 (16B-aligned frags) ----
  {
    const float4* src4 = (const float4*)(inps + b0 * 65);  // 130 float4, 16B aligned
    float4 v0 = src4[l];
    float4 v1 = src4[64 + l];
#pragma unroll
    for (int c = 0; c < 4; c++) {
      unsigned idx = l * 4 + c;
      unsigned row = idx / 65u, col = idx - row * 65u;
      xw[row * 72 + col] = (_Float16)((const float*)&v0)[c];
    }
#pragma unroll
    for (int c = 0; c < 4; c++) {
      unsigned idx = (64 + l) * 4 + c;
      unsigned row = idx / 65u, col = idx - row * 65u;
      xw[row * 72 + col] = (_Float16)((const float*)&v1)[c];
    }
    if (l < 2) {
      float4 v2 = src4[128 + l];
#pragma unroll
      for (int c = 0; c < 4; c++) {
        unsigned idx = (128 + l) * 4 + c;
        unsigned row = idx / 65u, col = idx - row * 65u;
        xw[row * 72 + col] = (_Float16)((const float*)&v2)[c];
      }
    }
  }
  __syncthreads();

  // A-frags of x: lane holds row m, k = t*32 + q*8 + j  (ds_read_b128)
  half8 ax[2];
#pragma unroll
  for (int t = 0; t < 2; t++)
    ax[t] = *(const half8*)(xw + m * 72 + t * 32 + q * 8);

  // matvec: w_pre C-layout (row=q*4+r, unit=m+16g)
  float4v acc[4];
#pragma unroll
  for (int g = 0; g < 4; g++) { acc[g][0] = 0.f; acc[g][1] = 0.f; acc[g][2] = 0.f; acc[g][3] = 0.f; }
#pragma unroll
  for (int g = 0; g < 4; g++)
#pragma unroll
    for (int t = 0; t < 2; t++)
      acc[g] = __builtin_amdgcn_mfma_f32_16x16x32_f16(ax[t], f_tw[t * 4 + g], acc[g], 0, 0, 0);

  // epilogue 1: tanh pair, penalties, dt -> LDS (f16) for A-relayout
  float yv[4];
#pragma unroll
  for (int r = 0; r < 4; r++) yv[r] = (float)xw[(q * 4 + r) * 72 + 64];
  float dtv[4][4], stv[4][4];
  float pint = 0.f, pneut = 0.f;
#pragma unroll
  for (int g = 0; g < 4; g++)
#pragma unroll
    for (int r = 0; r < 4; r++) {
      float wpre = acc[g][r] + tbv[g];
      float w1 = wpre + twyv[g] * yv[r];
      float w2 = wpre - twyv[g] * yv[r];
      float t1 = fast_tanh(w1), t2 = fast_tanh(w2);
      float dt = t1 - t2, st = t1 + t2;
      dtv[g][r] = dt; stv[g][r] = st;
      if (act) {
        float a1 = 1.f - t1 * t1, a2 = 1.f - t2 * t2;
        pint += a1 * a1 + a2 * a2;
        float nv = t2 * w2 - t1 * w1;
        pneut += nv * nv;
        dw[(q * 4 + r) * 72 + m + 16 * g] = (_Float16)dt;  // same-wave LDS round-trip
      }
    }

  // A-frags of dt (rows 8..15 garbage -> only unused C rows)
  half8 adt[2];
#pragma unroll
  for (int t = 0; t < 2; t++)
    adt[t] = *(const half8*)(dw + m * 72 + t * 32 + q * 8);

  float4v rxt[4], rtt[4];
#pragma unroll
  for (int g = 0; g < 4; g++) {
    rxt[g][0] = 0.f; rxt[g][1] = 0.f; rxt[g][2] = 0.f; rxt[g][3] = 0.f;
    rtt[g][0] = 0.f; rtt[g][1] = 0.f; rtt[g][2] = 0.f; rtt[g][3] = 0.f;
  }
#pragma unroll
  for (int g = 0; g < 4; g++)
#pragma unroll
    for (int t = 0; t < 2; t++) {
      rxt[g] = __builtin_amdgcn_mfma_f32_16x16x32_f16(adt[t], f_qxt[t * 4 + g], rxt[g], 0, 0, 0);
      rtt[g] = __builtin_amdgcn_mfma_f32_16x16x32_f16(adt[t], f_qtt[t * 4 + g], rtt[g], 0, 0, 0);
    }

  // final assembly: per (row=q*4+r, i=m+16g), reduce over g then lanes m
  float creg[4] = {0.f, 0.f, 0.f, 0.f};
#pragma unroll
  for (int g = 0; g < 4; g++)
#pragma unroll
    for (int r = 0; r < 4; r++) {
      float xv = (float)xw[(q * 4 + r) * 72 + m + 16 * g];
      creg[r] += xv * (2.f * yv[r] * qxyv[g] + rxt[g][r])
               + yv[r] * stv[g][r] * qytv[g]
               + 0.5f * stv[g][r] * rtt[g][r]
               + lintv[g] * dtv[g][r];
    }
#pragma unroll
  for (int r = 0; r < 4; r++) {
    float c = creg[r];
    c += __shfl_xor(c, 1); c += __shfl_xor(c, 2);
    c += __shfl_xor(c, 4); c += __shfl_xor(c, 8);
    if (act && m == 0) out[b0 + q * 4 + r] = 1.f + 2.f * yv[r] * liny + c;
  }

  // penalties: wave reduce -> per-block partials in ws (NO atomics: R6's 60 us
  // was 4096 same-line device-scope atomics serializing at ~15 ns each)
#pragma unroll
  for (int off = 1; off < 64; off <<= 1) {
    pint += __shfl_xor(pint, off);
    pneut += __shfl_xor(pneut, off);
  }
  if (l == 0) { s_red[wib] = pint; s_red[4 + wib] = pneut; }
  __syncthreads();
  if (tid == 0) {
    wsf[WS_P1 + blockIdx.x] = s_red[0] + s_red[1] + s_red[2] + s_red[3];
    wsf[WS_P2 + blockIdx.x] = s_red[4] + s_red[5] + s_red[6] + s_red[7];
  }
}

__global__ __launch_bounds__(512) void reduce_kernel(const float* __restrict__ wsf,
                                                     float* __restrict__ out) {
  __shared__ float s[16];
  const int tid = threadIdx.x;
  float a = wsf[WS_P1 + tid];
  float b = wsf[WS_P2 + tid];
#pragma unroll
  for (int off = 1; off < 64; off <<= 1) {
    a += __shfl_xor(a, off);
    b += __shfl_xor(b, off);
  }
  const int w = tid >> 6, l = tid & 63;
  if (l == 0) { s[w] = a; s[8 + w] = b; }
  __syncthreads();
  if (tid == 0) {
    float sa = 0.f, sb = 0.f;
#pragma unroll
    for (int i = 0; i < 8; i++) { sa += s[i]; sb += s[8 + i]; }
    out[B_SZ] = sa * (1.f / 300.f);
    out[B_SZ + 1] = sb;
  }
}

extern "C" void kernel_launch(void* const* d_in, const int* in_sizes, int n_in,
                              void* d_out, int out_size, void* d_ws, size_t ws_size,
                              hipStream_t stream) {
  const float* inps = (const float*)d_in[0];
  const float* tw   = (const float*)d_in[1];
  const float* tb   = (const float*)d_in[2];
  const float* mw   = (const float*)d_in[3];
  float* out = (float*)d_out;
  float* wsf = (float*)d_ws;
  setup_kernel<<<50, 256, 0, stream>>>(mw, tw, wsf);
  main_kernel<<<GRID, BLOCK, 0, stream>>>(inps, tb, wsf, out);
  reduce_kernel<<<1, 512, 0, stream>>>(wsf, out);
}

// Round 9
// 70.182 us; speedup vs baseline: 1.7195x; 1.0147x over previous
//
#include <hip/hip_runtime.h>

#define B_SZ 16384
#define N_SP 129
#define GRID 1024
#define BLOCK 256

typedef _Float16 half8 __attribute__((ext_vector_type(8)));
typedef float float4v __attribute__((ext_vector_type(4)));

// ws layout:
//   halves [0, 12288) (= floats [0,6144)): 24 B-frags, 64 lanes x 8 f16 each;
//     frag = tbl*8 + t*4 + g (tbl: 0=tw 1=qxt 2=qtt_sym), element ((frag*64+lane)*8+j)
//   floats: twy[64] qxy[64] qyt[64] lint[64] liny | p1[1024] p2[1024]
#define WS_TWY  6144
#define WS_QXY  6208
#define WS_QYT  6272
#define WS_LINT 6336
#define WS_LINY 6400
#define WS_P1   6464
#define WS_P2   7488

// index into main_w for quadratic pair (i<j), N=129: N + i*(2N-i-1)/2 + (j-i-1)
__device__ __forceinline__ int qidx(int i, int j) {
  return N_SP + i * (2 * N_SP - i - 1) / 2 + (j - i - 1);
}

// tanh(x) = 1 - 2/(e^{2x}+1): monotone, stable both tails
__device__ __forceinline__ float fast_tanh(float x) {
  float xc = fminf(fmaxf(x, -15.f), 15.f);
  float e = __expf(2.f * xc);
  return 1.f - 2.f / (e + 1.f);
}

__global__ void setup_kernel(const float* __restrict__ mw, const float* __restrict__ tw,
                             float* __restrict__ wsf) {
  int t = blockIdx.x * blockDim.x + threadIdx.x;
  if (t < 12288) {
    int frag = t >> 9, e = t & 511;
    int lane = e >> 3, j = e & 7;
    int tbl = frag >> 3, tg = frag & 7;
    int kt = tg >> 2, g = tg & 3;
    int k = kt * 32 + (lane >> 4) * 8 + j;   // K index (d or u), 0..63
    int n = (lane & 15) + 16 * g;            // N index (unit or i), 0..63
    float v;
    if (tbl == 0) {
      v = tw[n * 65 + k];                    // B[k][n] = tw[n][k]
    } else if (tbl == 1) {
      v = mw[qidx(n, 65 + k)];               // Qxt[i=n][u=k]
    } else {
      v = 0.f;
      if (n != k) {
        int a = n < k ? n : k, b = n < k ? k : n;
        v = mw[qidx(65 + a, 65 + b)];        // Qtt_sym
      }
    }
    ((_Float16*)wsf)[t] = (_Float16)v;
  } else if (t < 12352) {
    int u = t - 12288; wsf[WS_TWY + u] = tw[u * 65 + 64];
  } else if (t < 12416) {
    int i = t - 12352; wsf[WS_QXY + i] = mw[qidx(i, 64)];
  } else if (t < 12480) {
    int u = t - 12416; wsf[WS_QYT + u] = mw[qidx(64, 65 + u)];
  } else if (t < 12544) {
    int u = t - 12480; wsf[WS_LINT + u] = mw[65 + u];
  } else if (t == 12544) {
    wsf[WS_LINY] = mw[64];
  }
}

// 16 rows per block; 4 waves split the 64-unit dimension (wave wib owns
// units u = 16*wib + m). Shared x/dt tiles; B-frags block-staged into LDS
// via contiguous coalesced copy (defeats the R6-R8 register-sinking issue).
__global__ __launch_bounds__(BLOCK, 4) void main_kernel(
    const float* __restrict__ inps, const float* __restrict__ tb,
    float* __restrict__ wsf, float* __restrict__ out) {
  __shared__ __align__(16) _Float16 s_frag[12288];  // 24 KB, raw copy of ws frags
  __shared__ __align__(16) _Float16 s_x[1152];      // 16 rows x stride 72
  __shared__ __align__(16) _Float16 s_dt[1152];
  __shared__ float s_part[64];                      // 4 slices x 16 rows
  __shared__ float s_red[8];

  const int tid = threadIdx.x;
  const int l = tid & 63, wib = tid >> 6;
  const int b0 = blockIdx.x << 4;   // 16 rows/block
  const int q = l >> 4, m = l & 15;
  const int u = (wib << 4) + m;     // this lane's unit / i index

  // ---- frag staging: contiguous coalesced copy ws -> LDS (6 dwordx4/thread) ----
  {
    const float4* wsv = (const float4*)wsf;
    float4* dst = (float4*)s_frag;
#pragma unroll
    for (int i = 0; i < 6; i++) dst[tid + 256 * i] = wsv[tid + 256 * i];
  }
  // ---- per-lane coefficient loads (1 each; L2-hot, issue early) ----
  const float twyv = wsf[WS_TWY + u];
  const float qxyv = wsf[WS_QXY + u];
  const float qytv = wsf[WS_QYT + u];
  const float lintv = wsf[WS_LINT + u];
  const float liny = wsf[WS_LINY];
  const float tbv = tb[u];

  // ---- x staging: 16 rows x 65 f32 = 260 float4 -> s_x f16 [16][72] ----
  {
    const float4* src4 = (const float4*)(inps + b0 * 65);  // 16B-aligned (4160 B/block)
    float4 v = src4[tid];
#pragma unroll
    for (int c = 0; c < 4; c++) {
      unsigned idx = tid * 4 + c;
      unsigned row = idx / 65u, col = idx - row * 65u;
      s_x[row * 72 + col] = (_Float16)((const float*)&v)[c];
    }
    if (tid < 4) {
      float4 v2 = src4[256 + tid];
#pragma unroll
      for (int c = 0; c < 4; c++) {
        unsigned idx = (256 + tid) * 4 + c;
        unsigned row = idx / 65u, col = idx - row * 65u;
        s_x[row * 72 + col] = (_Float16)((const float*)&v2)[c];
      }
    }
  }
  __syncthreads();

  const half8* fragv = (const half8*)s_frag;

  // A-frags of x (identical for all 4 waves): lane row m, k = t*32 + q*8 + j
  half8 ax0 = *(const half8*)(s_x + m * 72 + q * 8);
  half8 ax1 = *(const half8*)(s_x + m * 72 + 32 + q * 8);

  // matvec, unit-slice wib: C-layout (row=q*4+r, col=m -> unit u)
  float4v acc = {0.f, 0.f, 0.f, 0.f};
  acc = __builtin_amdgcn_mfma_f32_16x16x32_f16(ax0, fragv[(0 + wib) * 64 + l], acc, 0, 0, 0);
  acc = __builtin_amdgcn_mfma_f32_16x16x32_f16(ax1, fragv[(4 + wib) * 64 + l], acc, 0, 0, 0);

  // tanh pair + penalties; dt -> shared tile (all 64 units filled by 4 waves)
  float yv[4], dtv[4], stv[4];
  float pint = 0.f, pneut = 0.f;
#pragma unroll
  for (int r = 0; r < 4; r++) {
    yv[r] = (float)s_x[(q * 4 + r) * 72 + 64];
    float wpre = acc[r] + tbv;
    float w1 = wpre + twyv * yv[r];
    float w2 = wpre - twyv * yv[r];
    float t1 = fast_tanh(w1), t2 = fast_tanh(w2);
    dtv[r] = t1 - t2; stv[r] = t1 + t2;
    float a1 = 1.f - t1 * t1, a2 = 1.f - t2 * t2;
    pint += a1 * a1 + a2 * a2;
    float nv = t2 * w2 - t1 * w1;
    pneut += nv * nv;
    s_dt[(q * 4 + r) * 72 + u] = (_Float16)dtv[r];
  }
  __syncthreads();

  // A-frags of dt (full K=64, all rows valid)
  half8 ad0 = *(const half8*)(s_dt + m * 72 + q * 8);
  half8 ad1 = *(const half8*)(s_dt + m * 72 + 32 + q * 8);

  float4v rxt = {0.f, 0.f, 0.f, 0.f}, rtt = {0.f, 0.f, 0.f, 0.f};
  rxt = __builtin_amdgcn_mfma_f32_16x16x32_f16(ad0, fragv[(8 + wib) * 64 + l], rxt, 0, 0, 0);
  rxt = __builtin_amdgcn_mfma_f32_16x16x32_f16(ad1, fragv[(12 + wib) * 64 + l], rxt, 0, 0, 0);
  rtt = __builtin_amdgcn_mfma_f32_16x16x32_f16(ad0, fragv[(16 + wib) * 64 + l], rtt, 0, 0, 0);
  rtt = __builtin_amdgcn_mfma_f32_16x16x32_f16(ad1, fragv[(20 + wib) * 64 + l], rtt, 0, 0, 0);

  // per-(row, u) contribution; reduce over m (shfl), then over wib (LDS)
  float creg[4];
#pragma unroll
  for (int r = 0; r < 4; r++) {
    float xv = (float)s_x[(q * 4 + r) * 72 + u];
    float c = xv * (2.f * yv[r] * qxyv + rxt[r])
            + yv[r] * stv[r] * qytv
            + 0.5f * stv[r] * rtt[r]
            + lintv * dtv[r];
    c += __shfl_xor(c, 1); c += __shfl_xor(c, 2);
    c += __shfl_xor(c, 4); c += __shfl_xor(c, 8);
    creg[r] = c;
  }
  if (m == 0) {
#pragma unroll
    for (int r = 0; r < 4; r++) s_part[wib * 16 + q * 4 + r] = creg[r];
  }

  // penalties: wave reduce -> block partial (no atomics)
#pragma unroll
  for (int off = 1; off < 64; off <<= 1) {
    pint += __shfl_xor(pint, off);
    pneut += __shfl_xor(pneut, off);
  }
  if (l == 0) { s_red[wib] = pint; s_red[4 + wib] = pneut; }
  __syncthreads();

  if (tid < 16) {
    float c = s_part[tid] + s_part[16 + tid] + s_part[32 + tid] + s_part[48 + tid];
    float y = (float)s_x[tid * 72 + 64];
    out[b0 + tid] = 1.f + 2.f * y * liny + c;
  }
  if (tid == 0) {
    wsf[WS_P1 + blockIdx.x] = s_red[0] + s_red[1] + s_red[2] + s_red[3];
    wsf[WS_P2 + blockIdx.x] = s_red[4] + s_red[5] + s_red[6] + s_red[7];
  }
}

__global__ __launch_bounds__(1024) void reduce_kernel(const float* __restrict__ wsf,
                                                      float* __restrict__ out) {
  __shared__ float s[32];
  const int tid = threadIdx.x;
  float a = wsf[WS_P1 + tid];
  float b = wsf[WS_P2 + tid];
#pragma unroll
  for (int off = 1; off < 64; off <<= 1) {
    a += __shfl_xor(a, off);
    b += __shfl_xor(b, off);
  }
  const int w = tid >> 6, l = tid & 63;
  if (l == 0) { s[w] = a; s[16 + w] = b; }
  __syncthreads();
  if (tid == 0) {
    float sa = 0.f, sb = 0.f;
#pragma unroll
    for (int i = 0; i < 16; i++) { sa += s[i]; sb += s[16 + i]; }
    out[B_SZ] = sa * (1.f / 300.f);
    out[B_SZ + 1] = sb;
  }
}

extern "C" void kernel_launch(void* const* d_in, const int* in_sizes, int n_in,
                              void* d_out, int out_size, void* d_ws, size_t ws_size,
                              hipStream_t stream) {
  const float* inps = (const float*)d_in[0];
  const float* tw   = (const float*)d_in[1];
  const float* tb   = (const float*)d_in[2];
  const float* mw   = (const float*)d_in[3];
  float* out = (float*)d_out;
  float* wsf = (float*)d_ws;
  setup_kernel<<<50, 256, 0, stream>>>(mw, tw, wsf);
  main_kernel<<<GRID, BLOCK, 0, stream>>>(inps, tb, wsf, out);
  reduce_kernel<<<1, 1024, 0, stream>>>(wsf, out);
}

// Round 11
// 69.060 us; speedup vs baseline: 1.7474x; 1.0162x over previous
//
#include <hip/hip_runtime.h>

#define B_SZ 16384
#define N_SP 129
#define GRID 1024
#define BLOCK 256

typedef _Float16 half8 __attribute__((ext_vector_type(8)));
typedef float float4v __attribute__((ext_vector_type(4)));

// ws layout:
//   halves [0, 12288) (= floats [0,6144)): 24 B-frags, 64 lanes x 8 f16 each;
//     frag = tbl*8 + t*4 + g (tbl: 0=tw 1=qxt 2=qtt_sym), element ((frag*64+lane)*8+j)
//   floats: twy[64] qxy[64] qyt[64] lint[64] liny | p1[1024] p2[1024]
#define WS_TWY  6144
#define WS_QXY  6208
#define WS_QYT  6272
#define WS_LINT 6336
#define WS_LINY 6400
#define WS_P1   6464
#define WS_P2   7488

// index into main_w for quadratic pair (i<j), N=129: N + i*(2N-i-1)/2 + (j-i-1)
__device__ __forceinline__ int qidx(int i, int j) {
  return N_SP + i * (2 * N_SP - i - 1) / 2 + (j - i - 1);
}

// tanh(x) = 1 - 2/(e^{2x}+1): monotone, stable both tails
__device__ __forceinline__ float fast_tanh(float x) {
  float xc = fminf(fmaxf(x, -15.f), 15.f);
  float e = __expf(2.f * xc);
  return 1.f - 2.f / (e + 1.f);
}

__global__ void setup_kernel(const float* __restrict__ mw, const float* __restrict__ tw,
                             float* __restrict__ wsf) {
  int t = blockIdx.x * blockDim.x + threadIdx.x;
  if (t < 12288) {
    int frag = t >> 9, e = t & 511;
    int lane = e >> 3, j = e & 7;
    int tbl = frag >> 3, tg = frag & 7;
    int kt = tg >> 2, g = tg & 3;
    int k = kt * 32 + (lane >> 4) * 8 + j;   // K index (d or u), 0..63
    int n = (lane & 15) + 16 * g;            // N index (unit or i), 0..63
    float v;
    if (tbl == 0) {
      v = tw[n * 65 + k];                    // B[k][n] = tw[n][k]
    } else if (tbl == 1) {
      v = mw[qidx(n, 65 + k)];               // Qxt[i=n][u=k]
    } else {
      v = 0.f;
      if (n != k) {
        int a = n < k ? n : k, b = n < k ? k : n;
        v = mw[qidx(65 + a, 65 + b)];        // Qtt_sym
      }
    }
    ((_Float16*)wsf)[t] = (_Float16)v;
  } else if (t < 12352) {
    int u = t - 12288; wsf[WS_TWY + u] = tw[u * 65 + 64];
  } else if (t < 12416) {
    int i = t - 12352; wsf[WS_QXY + i] = mw[qidx(i, 64)];
  } else if (t < 12480) {
    int u = t - 12416; wsf[WS_QYT + u] = mw[qidx(64, 65 + u)];
  } else if (t < 12544) {
    int u = t - 12480; wsf[WS_LINT + u] = mw[65 + u];
  } else if (t == 12544) {
    wsf[WS_LINY] = mw[64];
  }
}

// 16 rows per block; 4 waves split the 64-unit dimension (wave wib owns
// units u = 16*wib + m). Shared x/dt tiles; B-frags block-staged into LDS
// via contiguous coalesced copy (defeats the R6-R8 register-sinking issue).
__global__ __launch_bounds__(BLOCK, 4) void main_kernel(
    const float* __restrict__ inps, const float* __restrict__ tb,
    float* __restrict__ wsf, float* __restrict__ out) {
  __shared__ __align__(16) _Float16 s_frag[12288];  // 24 KB, raw copy of ws frags
  __shared__ __align__(16) _Float16 s_x[1152];      // 16 rows x stride 72
  __shared__ __align__(16) _Float16 s_dt[1152];
  __shared__ float s_part[64];                      // 4 slices x 16 rows
  __shared__ float s_red[8];

  const int tid = threadIdx.x;
  const int l = tid & 63, wib = tid >> 6;
  const int b0 = blockIdx.x << 4;   // 16 rows/block
  const int q = l >> 4, m = l & 15;
  const int u = (wib << 4) + m;     // this lane's unit / i index

  // ---- frag staging: contiguous coalesced copy ws -> LDS (6 dwordx4/thread) ----
  {
    const float4* wsv = (const float4*)wsf;
    float4* dst = (float4*)s_frag;
#pragma unroll
    for (int i = 0; i < 6; i++) dst[tid + 256 * i] = wsv[tid + 256 * i];
  }
  // ---- per-lane coefficient loads (1 each; L2-hot, issue early) ----
  const float twyv = wsf[WS_TWY + u];
  const float qxyv = wsf[WS_QXY + u];
  const float qytv = wsf[WS_QYT + u];
  const float lintv = wsf[WS_LINT + u];
  const float liny = wsf[WS_LINY];
  const float tbv = tb[u];

  // ---- x staging: 16 rows x 65 f32 = 260 float4 -> s_x f16 [16][72] ----
  {
    const float4* src4 = (const float4*)(inps + b0 * 65);  // 16B-aligned (4160 B/block)
    float4 v = src4[tid];
#pragma unroll
    for (int c = 0; c < 4; c++) {
      unsigned idx = tid * 4 + c;
      unsigned row = idx / 65u, col = idx - row * 65u;
      s_x[row * 72 + col] = (_Float16)((const float*)&v)[c];
    }
    if (tid < 4) {
      float4 v2 = src4[256 + tid];
#pragma unroll
      for (int c = 0; c < 4; c++) {
        unsigned idx = (256 + tid) * 4 + c;
        unsigned row = idx / 65u, col = idx - row * 65u;
        s_x[row * 72 + col] = (_Float16)((const float*)&v2)[c];
      }
    }
  }
  __syncthreads();

  const half8* fragv = (const half8*)s_frag;

  // A-frags of x (identical for all 4 waves): lane row m, k = t*32 + q*8 + j
  half8 ax0 = *(const half8*)(s_x + m * 72 + q * 8);
  half8 ax1 = *(const half8*)(s_x + m * 72 + 32 + q * 8);

  // matvec, unit-slice wib: C-layout (row=q*4+r, col=m -> unit u)
  float4v acc = {0.f, 0.f, 0.f, 0.f};
  acc = __builtin_amdgcn_mfma_f32_16x16x32_f16(ax0, fragv[(0 + wib) * 64 + l], acc, 0, 0, 0);
  acc = __builtin_amdgcn_mfma_f32_16x16x32_f16(ax1, fragv[(4 + wib) * 64 + l], acc, 0, 0, 0);

  // tanh pair + penalties; dt -> shared tile (all 64 units filled by 4 waves)
  float yv[4], dtv[4], stv[4];
  float pint = 0.f, pneut = 0.f;
#pragma unroll
  for (int r = 0; r < 4; r++) {
    yv[r] = (float)s_x[(q * 4 + r) * 72 + 64];
    float wpre = acc[r] + tbv;
    float w1 = wpre + twyv * yv[r];
    float w2 = wpre - twyv * yv[r];
    float t1 = fast_tanh(w1), t2 = fast_tanh(w2);
    dtv[r] = t1 - t2; stv[r] = t1 + t2;
    float a1 = 1.f - t1 * t1, a2 = 1.f - t2 * t2;
    pint += a1 * a1 + a2 * a2;
    float nv = t2 * w2 - t1 * w1;
    pneut += nv * nv;
    s_dt[(q * 4 + r) * 72 + u] = (_Float16)dtv[r];
  }
  __syncthreads();

  // A-frags of dt (full K=64, all rows valid)
  half8 ad0 = *(const half8*)(s_dt + m * 72 + q * 8);
  half8 ad1 = *(const half8*)(s_dt + m * 72 + 32 + q * 8);

  float4v rxt = {0.f, 0.f, 0.f, 0.f}, rtt = {0.f, 0.f, 0.f, 0.f};
  rxt = __builtin_amdgcn_mfma_f32_16x16x32_f16(ad0, fragv[(8 + wib) * 64 + l], rxt, 0, 0, 0);
  rxt = __builtin_amdgcn_mfma_f32_16x16x32_f16(ad1, fragv[(12 + wib) * 64 + l], rxt, 0, 0, 0);
  rtt = __builtin_amdgcn_mfma_f32_16x16x32_f16(ad0, fragv[(16 + wib) * 64 + l], rtt, 0, 0, 0);
  rtt = __builtin_amdgcn_mfma_f32_16x16x32_f16(ad1, fragv[(20 + wib) * 64 + l], rtt, 0, 0, 0);

  // per-(row, u) contribution; reduce over m (shfl), then over wib (LDS)
  float creg[4];
#pragma unroll
  for (int r = 0; r < 4; r++) {
    float xv = (float)s_x[(q * 4 + r) * 72 + u];
    float c = xv * (2.f * yv[r] * qxyv + rxt[r])
            + yv[r] * stv[r] * qytv
            + 0.5f * stv[r] * rtt[r]
            + lintv * dtv[r];
    c += __shfl_xor(c, 1); c += __shfl_xor(c, 2);
    c += __shfl_xor(c, 4); c += __shfl_xor(c, 8);
    creg[r] = c;
  }
  if (m == 0) {
#pragma unroll
    for (int r = 0; r < 4; r++) s_part[wib * 16 + q * 4 + r] = creg[r];
  }

  // penalties: wave reduce -> block partial (no atomics)
#pragma unroll
  for (int off = 1; off < 64; off <<= 1) {
    pint += __shfl_xor(pint, off);
    pneut += __shfl_xor(pneut, off);
  }
  if (l == 0) { s_red[wib] = pint; s_red[4 + wib] = pneut; }
  __syncthreads();

  if (tid < 16) {
    float c = s_part[tid] + s_part[16 + tid] + s_part[32 + tid] + s_part[48 + tid];
    float y = (float)s_x[tid * 72 + 64];
    out[b0 + tid] = 1.f + 2.f * y * liny + c;
  }
  if (tid == 0) {
    wsf[WS_P1 + blockIdx.x] = s_red[0] + s_red[1] + s_red[2] + s_red[3];
    wsf[WS_P2 + blockIdx.x] = s_red[4] + s_red[5] + s_red[6] + s_red[7];
  }
}

__global__ __launch_bounds__(1024) void reduce_kernel(const float* __restrict__ wsf,
                                                      float* __restrict__ out) {
  __shared__ float s[32];
  const int tid = threadIdx.x;
  float a = wsf[WS_P1 + tid];
  float b = wsf[WS_P2 + tid];
#pragma unroll
  for (int off = 1; off < 64; off <<= 1) {
    a += __shfl_xor(a, off);
    b += __shfl_xor(b, off);
  }
  const int w = tid >> 6, l = tid & 63;
  if (l == 0) { s[w] = a; s[16 + w] = b; }
  __syncthreads();
  if (tid == 0) {
    float sa = 0.f, sb = 0.f;
#pragma unroll
    for (int i = 0; i < 16; i++) { sa += s[i]; sb += s[16 + i]; }
    out[B_SZ] = sa * (1.f / 300.f);
    out[B_SZ + 1] = sb;
  }
}

extern "C" void kernel_launch(void* const* d_in, const int* in_sizes, int n_in,
                              void* d_out, int out_size, void* d_ws, size_t ws_size,
                              hipStream_t stream) {
  const float* inps = (const float*)d_in[0];
  const float* tw   = (const float*)d_in[1];
  const float* tb   = (const float*)d_in[2];
  const float* mw   = (const float*)d_in[3];
  float* out = (float*)d_out;
  float* wsf = (float*)d_ws;
  setup_kernel<<<50, 256, 0, stream>>>(mw, tw, wsf);
  main_kernel<<<GRID, BLOCK, 0, stream>>>(inps, tb, wsf, out);
  reduce_kernel<<<1, 1024, 0, stream>>>(wsf, out);
}